// Round 1
// baseline (591.923 us; speedup 1.0000x reference)
//
#include <hip/hip_runtime.h>

#define N_NODES 4096
#define N_EDGES 131072
#define BATCH   16
#define HDIM    16
#define FCDIM   20
#define BH      256              // BATCH*HDIM
#define ISD     0.17677669529663687f  // 1/sqrt(E/N) = 1/sqrt(32)

// f4get with COMPILE-TIME k folds to a member read (runtime k would force scratch!)
__device__ __forceinline__ float f4get(const float4& v, int k) {
    return k == 0 ? v.x : (k == 1 ? v.y : (k == 2 ? v.z : v.w));
}

// ---------------- setup: ew, G[b][j][k], invF, zero d_out + cnt -------------
__global__ void setup_kernel(const float* __restrict__ F, const float* __restrict__ W_in,
                             const float* __restrict__ fc1_0, const float* __restrict__ fc2_0,
                             const float* __restrict__ fc1_1, const float* __restrict__ fc2_1,
                             float* __restrict__ ew, float* __restrict__ G,
                             float* __restrict__ invF, float* __restrict__ out144,
                             int* __restrict__ cnt) {
    int t = threadIdx.x;
    if (t < 6) {
        const float* fc1 = (t < 3) ? fc1_0 : fc1_1;
        const float* fc2 = (t < 3) ? fc2_0 : fc2_1;
        int ty = t % 3;
        float s = 0.f;
        for (int f = 0; f < FCDIM; ++f) {
            float v = fc1[ty * FCDIM + f];
            v = v > 0.f ? v : 0.f;
            s += v * fc2[f];
        }
        ew[t] = s;
    }
    for (int idx = t; idx < BATCH * 3 * HDIM; idx += 256) {
        int b = idx / 48, r = idx % 48, j = r / HDIM, k = r % HDIM;
        float s = 0.f;
        for (int i = 0; i < 3; ++i) s += F[b * 9 + i * 3 + j] * W_in[i * HDIM + k];
        G[idx] = s;
    }
    if (t < BATCH) {
        const float* f = F + t * 9;
        float a00=f[0],a01=f[1],a02=f[2],a10=f[3],a11=f[4],a12=f[5],a20=f[6],a21=f[7],a22=f[8];
        float det = a00*(a11*a22-a12*a21) - a01*(a10*a22-a12*a20) + a02*(a10*a21-a11*a20);
        float id = 1.f/det;
        float* o = invF + t*9;
        o[0]=(a11*a22-a12*a21)*id; o[1]=(a02*a21-a01*a22)*id; o[2]=(a01*a12-a02*a11)*id;
        o[3]=(a12*a20-a10*a22)*id; o[4]=(a00*a22-a02*a20)*id; o[5]=(a02*a10-a00*a12)*id;
        o[6]=(a10*a21-a11*a20)*id; o[7]=(a01*a20-a00*a21)*id; o[8]=(a00*a11-a01*a10)*id;
    }
    if (t < 144) out144[t] = 0.f;
    for (int i = t; i < N_NODES; i += 256) cnt[i] = 0;
}

// ---------------- fused: h0 compute (blocks 0..1023) + edge hist (1024..1535)
__global__ void h0_hist_kernel(const float* __restrict__ pos, const float* __restrict__ G,
                               float* __restrict__ h0,
                               const int* __restrict__ edst, int* __restrict__ cnt) {
    int bid = blockIdx.x;
    int t = threadIdx.x;
    if (bid < 1024) {
        int id = bid * 256 + t;
        int n  = id >> 6;
        int c4 = (id & 63) << 2;
        int b  = c4 >> 4;
        int k  = c4 & 15;
        float p0 = pos[n*3+0], p1 = pos[n*3+1], p2 = pos[n*3+2];
        const float* g = G + b*48 + k;
        float4 r;
        r.x = p0*g[0] + p1*g[16] + p2*g[32];
        r.y = p0*g[1] + p1*g[17] + p2*g[33];
        r.z = p0*g[2] + p1*g[18] + p2*g[34];
        r.w = p0*g[3] + p1*g[19] + p2*g[35];
        *(float4*)(h0 + n*BH + c4) = r;
    } else {
        int e = (bid - 1024) * 256 + t;
        if (e < N_EDGES) atomicAdd(&cnt[edst[e]], 1);
    }
}

// ---------------- CSR build -------------------------------------------------
__global__ void scan_kernel(const int* __restrict__ cnt, int* __restrict__ off,
                            int* __restrict__ cursor) {
    __shared__ int wsum[4];
    int t = threadIdx.x;
    int lane = t & 63, wave = t >> 6;
    int base = t * 16;
    int loc[16];
    int s = 0;
    #pragma unroll
    for (int i = 0; i < 16; ++i) { loc[i] = s; s += cnt[base + i]; }
    int pre = s;
    #pragma unroll
    for (int o = 1; o < 64; o <<= 1) {
        int v = __shfl_up(pre, o);
        if (lane >= o) pre += v;
    }
    if (lane == 63) wsum[wave] = pre;
    __syncthreads();
    int woff = 0;
    #pragma unroll
    for (int w = 0; w < 4; ++w) if (w < wave) woff += wsum[w];
    int excl = woff + pre - s;
    #pragma unroll
    for (int i = 0; i < 16; ++i) {
        int v = excl + loc[i];
        off[base + i] = v;
        cursor[base + i] = v;
    }
    if (t == 255) off[N_NODES] = excl + s;
}
__global__ void fill_kernel(const int* __restrict__ src, const int* __restrict__ dst,
                            const int* __restrict__ typ, int* __restrict__ cursor,
                            int* __restrict__ sedge) {
    int e = blockIdx.x * 256 + threadIdx.x;
    if (e < N_EDGES) {
        int p = atomicAdd(&cursor[dst[e]], 1);
        sedge[p] = src[e] | (typ[e] << 16);
    }
}

// ---------------- one GCN layer: gather+scale, @W, relu ---------------------
// 2 waves per dst node (half-row each, float2 lanes); grid 2048 -> 32 waves/CU
__global__ void layer_kernel(const float* __restrict__ h_in, float* __restrict__ h_out,
                             const int* __restrict__ off, const int* __restrict__ sedge,
                             const float* __restrict__ ew3, const float* __restrict__ W) {
    __shared__ float Wl[256];
    __shared__ float aggS[2][16*17 + 4];
    int t = threadIdx.x;
    Wl[t] = W[t];
    int wave = t >> 6, lane = t & 63;
    int node = wave >> 1;
    int half = wave & 1;
    int d = blockIdx.x * 2 + node;
    float e0 = ew3[0], e1 = ew3[1], e2 = ew3[2];
    int beg = off[d], end = off[d+1];
    int col = half * 128 + lane * 2;
    float2 acc = {0.f, 0.f};
    int it = beg;
    for (; it + 7 < end; it += 8) {
        int v[8]; float2 hv[8];
        #pragma unroll
        for (int u = 0; u < 8; ++u) v[u] = sedge[it + u];
        #pragma unroll
        for (int u = 0; u < 8; ++u)
            hv[u] = *(const float2*)(h_in + (v[u] & 0xFFFF) * BH + col);
        #pragma unroll
        for (int u = 0; u < 8; ++u) {
            int ty = v[u] >> 16;
            float wg = (ty == 0) ? e0 : (ty == 1 ? e1 : e2);
            acc.x += wg * hv[u].x; acc.y += wg * hv[u].y;
        }
    }
    for (; it < end; ++it) {
        int v = sedge[it];
        int ty = v >> 16;
        float wg = (ty == 0) ? e0 : (ty == 1 ? e1 : e2);
        float2 hv = *(const float2*)(h_in + (v & 0xFFFF) * BH + col);
        acc.x += wg * hv.x; acc.y += wg * hv.y;
    }
    int b = col >> 4, k0 = col & 15;
    aggS[node][b*17 + k0]     = acc.x * ISD;
    aggS[node][b*17 + k0 + 1] = acc.y * ISD;
    __syncthreads();
    int en = t >> 7, c2 = (t & 127) * 2;
    int eb = c2 >> 4, ek = c2 & 15;
    const float* arow = aggS[en] + eb * 17;
    float o0 = 0.f, o1 = 0.f;
    #pragma unroll
    for (int k = 0; k < 16; ++k) {
        float av = arow[k];
        o0 += av * Wl[k*16 + ek];
        o1 += av * Wl[k*16 + ek + 1];
    }
    int ed = blockIdx.x * 2 + en;
    float2 r;
    r.x = o0 > 0.f ? o0 : 0.f;
    r.y = o1 > 0.f ? o1 : 0.f;
    *(float2*)(h_out + ed*BH + c2) = r;
}

// ---------------- hout[n][b*3+p] = sum_k h2[n][b*16+k] * W_out[k][p] --------
__global__ void hout_kernel(const float* __restrict__ h2, const float* __restrict__ Wout,
                            float* __restrict__ hout) {
    __shared__ float Wo[48];
    int t = threadIdx.x;
    if (t < 48) Wo[t] = Wout[t];
    __syncthreads();
    int id = blockIdx.x * 256 + t;
    int n = id >> 4, b = id & 15;
    const float* hr = h2 + n*BH + b*HDIM;
    float s0=0.f, s1=0.f, s2=0.f;
    #pragma unroll
    for (int k = 0; k < 16; ++k) {
        float v = hr[k];
        s0 += v*Wo[k*3+0]; s1 += v*Wo[k*3+1]; s2 += v*Wo[k*3+2];
    }
    float* o = hout + n*48 + b*3;
    o[0]=s0; o[1]=s1; o[2]=s2;
}

// ---------------- a, c for first N edges ------------------------------------
__global__ void ac_kernel(const float* __restrict__ hout, const int* __restrict__ esrc,
                          const int* __restrict__ edst, const float* __restrict__ invF,
                          float* __restrict__ a, float* __restrict__ c) {
    __shared__ float iF[144];
    int t = threadIdx.x;
    if (t < 144) iF[t] = invF[t];
    __syncthreads();
    int id = blockIdx.x * 256 + t;
    int i = id >> 4, b = id & 15;
    int s = esrc[i], d = edst[i];
    float a0 = hout[s*48+b*3+0] - hout[d*48+b*3+0];
    float a1 = hout[s*48+b*3+1] - hout[d*48+b*3+1];
    float a2 = hout[s*48+b*3+2] - hout[d*48+b*3+2];
    float* ap = a + i*48 + b*3;
    ap[0]=a0; ap[1]=a1; ap[2]=a2;
    const float* m = iF + b*9;
    float* cp = c + i*48 + b*3;
    cp[0] = m[0]*a0 + m[1]*a1 + m[2]*a2;
    cp[1] = m[3]*a0 + m[4]*a1 + m[5]*a2;
    cp[2] = m[6]*a0 + m[7]*a1 + m[8]*a2;
}

// ---------------- fused stress: t-partial GEMM + c-contraction --------------
// stress[b,p,q] = sum_j (sum_i W2[i,j] a[i,bp]) c[j,bq].  The contraction is
// linear in the per-block partial t, so each block (128-i strip x 128-j tile)
// contracts its own t-tile against a staged c-tile and atomicAdds 144 floats.
// Eliminates the 26 MB partial write + 25 MB reduce read + 2 kernel launches.
// Main loop: 2-chunk-deep prefetch (16 rows, 16 loads in flight) so the
// vmcnt wait lands ~770 FMA-issue cycles after issue (covers HBM latency);
// 3 blocks/CU (LDS-limited: 24 KB sa + 25 KB sc) = 12 waves/CU.
__global__ __launch_bounds__(256, 3)
void stress_fused_kernel(const float* __restrict__ W2, const float* __restrict__ a,
                         const float* __restrict__ c, float* __restrict__ out) {
    __shared__ float sa[128 * 48];        // 24 KB a-strip [row][col]
    __shared__ float sc[128 * 49];        // 25.1 KB c-tile [jl][col], pad->49
    int t = threadIdx.x;
    int lane = t & 63;
    int wave = t >> 6;          // 0..3, wave owns cols cg..cg+11 (disjoint b)
    int cg   = wave * 12;
    int jb    = (blockIdx.x & 31) * 128;
    int strip = blockIdx.x >> 5;         // 0..31
    int i0    = strip * 128;
    // stage a-strip: 6144 floats = 1536 float4
    {
        const float4* ga = (const float4*)(a + (size_t)i0 * 48);
        float4* la = (float4*)sa;
        #pragma unroll
        for (int k = 0; k < 6; ++k) la[t + k * 256] = ga[t + k * 256];
    }
    // stage c-tile with pad-49 rows (scalar LDS writes; float4 stays in-row
    // since 48 % 4 == 0)
    {
        const float4* gc = (const float4*)(c + (size_t)jb * 48);
        #pragma unroll
        for (int k = 0; k < 6; ++k) {
            int id4 = t + k * 256;                 // 0..1535
            float4 v = gc[id4];
            int jl = (id4 * 4) / 48, col = (id4 * 4) % 48;
            float* d = &sc[jl * 49 + col];
            d[0] = v.x; d[1] = v.y; d[2] = v.z; d[3] = v.w;
        }
    }
    __syncthreads();
    int j = jb + lane * 2;
    const float* w2p = W2 + (size_t)i0 * N_NODES + j;
    float4 acc[2][3];
    #pragma unroll
    for (int jj = 0; jj < 2; ++jj)
        #pragma unroll
        for (int q = 0; q < 3; ++q) acc[jj][q] = make_float4(0.f,0.f,0.f,0.f);
    float2 wa[8], wb[8];
    #pragma unroll
    for (int u = 0; u < 8; ++u)
        wa[u] = *(const float2*)(w2p + (size_t)u * N_NODES);
    #pragma unroll
    for (int u = 0; u < 8; ++u)
        wb[u] = *(const float2*)(w2p + (size_t)(8 + u) * N_NODES);
    #pragma unroll 1
    for (int base = 0; base < 128; base += 16) {
        // issue next-chunk-pair loads (16 in flight; clamped tail loads are
        // harmless — never FMA'd)
        float2 wa2[8], wb2[8];
        #pragma unroll
        for (int u = 0; u < 8; ++u) {
            int r = base + 16 + u; if (r > 127) r = 127;
            wa2[u] = *(const float2*)(w2p + (size_t)r * N_NODES);
        }
        #pragma unroll
        for (int u = 0; u < 8; ++u) {
            int r = base + 24 + u; if (r > 127) r = 127;
            wb2[u] = *(const float2*)(w2p + (size_t)r * N_NODES);
        }
        // FMA rows base..base+7 (wa), a from LDS broadcast
        #pragma unroll
        for (int u = 0; u < 8; ++u) {
            const float* ar = &sa[(base + u) * 48 + cg];
            float4 x = *(const float4*)(ar);
            float4 y = *(const float4*)(ar + 4);
            float4 z = *(const float4*)(ar + 8);
            #pragma unroll
            for (int jj = 0; jj < 2; ++jj) {
                float wv = jj == 0 ? wa[u].x : wa[u].y;
                acc[jj][0].x += wv*x.x; acc[jj][0].y += wv*x.y;
                acc[jj][0].z += wv*x.z; acc[jj][0].w += wv*x.w;
                acc[jj][1].x += wv*y.x; acc[jj][1].y += wv*y.y;
                acc[jj][1].z += wv*y.z; acc[jj][1].w += wv*y.w;
                acc[jj][2].x += wv*z.x; acc[jj][2].y += wv*z.y;
                acc[jj][2].z += wv*z.z; acc[jj][2].w += wv*z.w;
            }
        }
        // FMA rows base+8..base+15 (wb)
        #pragma unroll
        for (int u = 0; u < 8; ++u) {
            const float* ar = &sa[(base + 8 + u) * 48 + cg];
            float4 x = *(const float4*)(ar);
            float4 y = *(const float4*)(ar + 4);
            float4 z = *(const float4*)(ar + 8);
            #pragma unroll
            for (int jj = 0; jj < 2; ++jj) {
                float wv = jj == 0 ? wb[u].x : wb[u].y;
                acc[jj][0].x += wv*x.x; acc[jj][0].y += wv*x.y;
                acc[jj][0].z += wv*x.z; acc[jj][0].w += wv*x.w;
                acc[jj][1].x += wv*y.x; acc[jj][1].y += wv*y.y;
                acc[jj][1].z += wv*y.z; acc[jj][1].w += wv*y.w;
                acc[jj][2].x += wv*z.x; acc[jj][2].y += wv*z.y;
                acc[jj][2].z += wv*z.z; acc[jj][2].w += wv*z.w;
            }
        }
        // rotate (compiler emits the vmcnt wait here, ~770 issue-cycles after
        // the loads went out)
        #pragma unroll
        for (int u = 0; u < 8; ++u) { wa[u] = wa2[u]; wb[u] = wb2[u]; }
    }
    // epilogue: contract t-tile with c-tile.  thread's 2 j-values x 12 cols.
    // sc read stride: lane word-stride 2*49=98 = 2 (mod 32) -> 2 lanes/bank, free.
    float s[36];
    #pragma unroll
    for (int m = 0; m < 36; ++m) s[m] = 0.f;
    #pragma unroll
    for (int jj = 0; jj < 2; ++jj) {
        const float* cvp = &sc[(lane * 2 + jj) * 49 + cg];
        float cv[12];
        #pragma unroll
        for (int m = 0; m < 12; ++m) cv[m] = cvp[m];
        #pragma unroll
        for (int cc = 0; cc < 12; ++cc) {
            float tv = f4get(acc[jj][cc >> 2], cc & 3);
            int qb = (cc / 3) * 3;
            s[cc*3+0] += tv * cv[qb+0];
            s[cc*3+1] += tv * cv[qb+1];
            s[cc*3+2] += tv * cv[qb+2];
        }
    }
    // wave butterfly reduce (lanes hold disjoint j, same 36 outputs)
    #pragma unroll
    for (int m = 0; m < 36; ++m) {
        float v = s[m];
        #pragma unroll
        for (int o = 1; o < 64; o <<= 1) v += __shfl_xor(v, o);
        s[m] = v;
    }
    // waves own disjoint b-groups -> 144 atomics per block, 1024 per address
    // over the whole kernel (~35 adds/us/address: negligible contention)
    if (lane == 0) {
        #pragma unroll
        for (int m = 0; m < 36; ++m) {
            int cc = m / 3, q = m % 3;
            int bp = cg + cc;
            atomicAdd(&out[(bp / 3) * 9 + (bp % 3) * 3 + q], s[m]);
        }
    }
}

extern "C" void kernel_launch(void* const* d_in, const int* in_sizes, int n_in,
                              void* d_out, int out_size, void* d_ws, size_t ws_size,
                              hipStream_t stream) {
    const float* F     = (const float*)d_in[0];
    const float* pos   = (const float*)d_in[1];
    const int*   esrc  = (const int*)d_in[2];
    const int*   edst  = (const int*)d_in[3];
    const int*   etyp  = (const int*)d_in[4];
    const float* W_in  = (const float*)d_in[5];
    const float* fc1_0 = (const float*)d_in[6];
    const float* fc2_0 = (const float*)d_in[7];
    const float* W_0   = (const float*)d_in[8];
    const float* fc1_1 = (const float*)d_in[9];
    const float* fc2_1 = (const float*)d_in[10];
    const float* W_1   = (const float*)d_in[11];
    const float* W_out = (const float*)d_in[12];
    const float* w2    = (const float*)d_in[13];
    float* out = (float*)d_out;

    float* ws   = (float*)d_ws;
    float* ew   = ws;                     // 6
    float* G    = ws + 16;                // 768
    float* invF = ws + 800;               // 144
    float* bufA = ws + 1024;              // N*256
    float* bufB = bufA + N_NODES*BH;      // N*256
    float* hout = bufB + N_NODES*BH;      // N*48
    float* aArr = hout + N_NODES*48;      // N*48
    float* cArr = aArr + N_NODES*48;      // N*48
    int* cnt    = (int*)(cArr + N_NODES*48);
    int* off    = cnt + N_NODES;          // N+1
    int* cursor = off + N_NODES + 1;      // N
    int* sedge  = cursor + N_NODES;       // E

    setup_kernel<<<1, 256, 0, stream>>>(F, W_in, fc1_0, fc2_0, fc1_1, fc2_1, ew, G, invF, out, cnt);
    h0_hist_kernel<<<1536, 256, 0, stream>>>(pos, G, bufA, edst, cnt);
    scan_kernel<<<1, 256, 0, stream>>>(cnt, off, cursor);
    fill_kernel<<<512, 256, 0, stream>>>(esrc, edst, etyp, cursor, sedge);
    layer_kernel<<<2048, 256, 0, stream>>>(bufA, bufB, off, sedge, ew,     W_0);
    layer_kernel<<<2048, 256, 0, stream>>>(bufB, bufA, off, sedge, ew + 3, W_1);
    hout_kernel<<<256, 256, 0, stream>>>(bufA, W_out, hout);
    ac_kernel<<<256, 256, 0, stream>>>(hout, esrc, edst, invF, aArr, cArr);
    stress_fused_kernel<<<1024, 256, 0, stream>>>(w2, aArr, cArr, out);
}

// Round 2
// 213.449 us; speedup vs baseline: 2.7731x; 2.7731x over previous
//
#include <hip/hip_runtime.h>

#define N_NODES 4096
#define N_EDGES 131072
#define BATCH   16
#define HDIM    16
#define FCDIM   20
#define BH      256              // BATCH*HDIM
#define ISD     0.17677669529663687f  // 1/sqrt(E/N) = 1/sqrt(32)
#define NBSTRESS 2048            // stress grid: 64 i-strips x 32 j-tiles

// f4get with COMPILE-TIME k folds to a member read (runtime k would force scratch!)
__device__ __forceinline__ float f4get(const float4& v, int k) {
    return k == 0 ? v.x : (k == 1 ? v.y : (k == 2 ? v.z : v.w));
}

// ---- DPP wave64 sum (LLVM atomic-optimizer sequence) — pure VALU, no DS ----
// total lands in lanes 48..63 (use lane 63).
template<int CTRL, int RM>
__device__ __forceinline__ float dpp_add(float v) {
    int sh = __builtin_amdgcn_update_dpp(0, __float_as_int(v), CTRL, RM, 0xF, true);
    return v + __int_as_float(sh);
}
__device__ __forceinline__ float wave_sum64(float v) {
    v = dpp_add<0xB1, 0xF>(v);   // quad_perm [1,0,3,2]  (xor 1)
    v = dpp_add<0x4E, 0xF>(v);   // quad_perm [2,3,0,1]  (xor 2)
    v = dpp_add<0x141,0xF>(v);   // row_half_mirror      (fold 4<->4)
    v = dpp_add<0x140,0xF>(v);   // row_mirror           (fold 8<->8)
    v = dpp_add<0x142,0xA>(v);   // row_bcast15 -> rows 1,3
    v = dpp_add<0x143,0xC>(v);   // row_bcast31 -> rows 2,3
    return v;
}

// ---------------- setup: ew, G[b][j][k], invF, zero d_out + cnt -------------
__global__ void setup_kernel(const float* __restrict__ F, const float* __restrict__ W_in,
                             const float* __restrict__ fc1_0, const float* __restrict__ fc2_0,
                             const float* __restrict__ fc1_1, const float* __restrict__ fc2_1,
                             float* __restrict__ ew, float* __restrict__ G,
                             float* __restrict__ invF, float* __restrict__ out144,
                             int* __restrict__ cnt) {
    int t = threadIdx.x;
    if (t < 6) {
        const float* fc1 = (t < 3) ? fc1_0 : fc1_1;
        const float* fc2 = (t < 3) ? fc2_0 : fc2_1;
        int ty = t % 3;
        float s = 0.f;
        for (int f = 0; f < FCDIM; ++f) {
            float v = fc1[ty * FCDIM + f];
            v = v > 0.f ? v : 0.f;
            s += v * fc2[f];
        }
        ew[t] = s;
    }
    for (int idx = t; idx < BATCH * 3 * HDIM; idx += 256) {
        int b = idx / 48, r = idx % 48, j = r / HDIM, k = r % HDIM;
        float s = 0.f;
        for (int i = 0; i < 3; ++i) s += F[b * 9 + i * 3 + j] * W_in[i * HDIM + k];
        G[idx] = s;
    }
    if (t < BATCH) {
        const float* f = F + t * 9;
        float a00=f[0],a01=f[1],a02=f[2],a10=f[3],a11=f[4],a12=f[5],a20=f[6],a21=f[7],a22=f[8];
        float det = a00*(a11*a22-a12*a21) - a01*(a10*a22-a12*a20) + a02*(a10*a21-a11*a20);
        float id = 1.f/det;
        float* o = invF + t*9;
        o[0]=(a11*a22-a12*a21)*id; o[1]=(a02*a21-a01*a22)*id; o[2]=(a01*a12-a02*a11)*id;
        o[3]=(a12*a20-a10*a22)*id; o[4]=(a00*a22-a02*a20)*id; o[5]=(a02*a10-a00*a12)*id;
        o[6]=(a10*a21-a11*a20)*id; o[7]=(a01*a20-a00*a21)*id; o[8]=(a00*a11-a01*a10)*id;
    }
    if (t < 144) out144[t] = 0.f;
    for (int i = t; i < N_NODES; i += 256) cnt[i] = 0;
}

// ---------------- fused: h0 compute (blocks 0..1023) + edge hist (1024..1535)
__global__ void h0_hist_kernel(const float* __restrict__ pos, const float* __restrict__ G,
                               float* __restrict__ h0,
                               const int* __restrict__ edst, int* __restrict__ cnt) {
    int bid = blockIdx.x;
    int t = threadIdx.x;
    if (bid < 1024) {
        int id = bid * 256 + t;
        int n  = id >> 6;
        int c4 = (id & 63) << 2;
        int b  = c4 >> 4;
        int k  = c4 & 15;
        float p0 = pos[n*3+0], p1 = pos[n*3+1], p2 = pos[n*3+2];
        const float* g = G + b*48 + k;
        float4 r;
        r.x = p0*g[0] + p1*g[16] + p2*g[32];
        r.y = p0*g[1] + p1*g[17] + p2*g[33];
        r.z = p0*g[2] + p1*g[18] + p2*g[34];
        r.w = p0*g[3] + p1*g[19] + p2*g[35];
        *(float4*)(h0 + n*BH + c4) = r;
    } else {
        int e = (bid - 1024) * 256 + t;
        if (e < N_EDGES) atomicAdd(&cnt[edst[e]], 1);
    }
}

// ---------------- CSR build -------------------------------------------------
__global__ void scan_kernel(const int* __restrict__ cnt, int* __restrict__ off,
                            int* __restrict__ cursor) {
    __shared__ int wsum[4];
    int t = threadIdx.x;
    int lane = t & 63, wave = t >> 6;
    int base = t * 16;
    int loc[16];
    int s = 0;
    #pragma unroll
    for (int i = 0; i < 16; ++i) { loc[i] = s; s += cnt[base + i]; }
    int pre = s;
    #pragma unroll
    for (int o = 1; o < 64; o <<= 1) {
        int v = __shfl_up(pre, o);
        if (lane >= o) pre += v;
    }
    if (lane == 63) wsum[wave] = pre;
    __syncthreads();
    int woff = 0;
    #pragma unroll
    for (int w = 0; w < 4; ++w) if (w < wave) woff += wsum[w];
    int excl = woff + pre - s;
    #pragma unroll
    for (int i = 0; i < 16; ++i) {
        int v = excl + loc[i];
        off[base + i] = v;
        cursor[base + i] = v;
    }
    if (t == 255) off[N_NODES] = excl + s;
}
__global__ void fill_kernel(const int* __restrict__ src, const int* __restrict__ dst,
                            const int* __restrict__ typ, int* __restrict__ cursor,
                            int* __restrict__ sedge) {
    int e = blockIdx.x * 256 + threadIdx.x;
    if (e < N_EDGES) {
        int p = atomicAdd(&cursor[dst[e]], 1);
        sedge[p] = src[e] | (typ[e] << 16);
    }
}

// ---------------- one GCN layer: gather+scale, @W, relu ---------------------
// 2 waves per dst node (half-row each, float2 lanes); grid 2048 -> 32 waves/CU
__global__ void layer_kernel(const float* __restrict__ h_in, float* __restrict__ h_out,
                             const int* __restrict__ off, const int* __restrict__ sedge,
                             const float* __restrict__ ew3, const float* __restrict__ W) {
    __shared__ float Wl[256];
    __shared__ float aggS[2][16*17 + 4];
    int t = threadIdx.x;
    Wl[t] = W[t];
    int wave = t >> 6, lane = t & 63;
    int node = wave >> 1;
    int half = wave & 1;
    int d = blockIdx.x * 2 + node;
    float e0 = ew3[0], e1 = ew3[1], e2 = ew3[2];
    int beg = off[d], end = off[d+1];
    int col = half * 128 + lane * 2;
    float2 acc = {0.f, 0.f};
    int it = beg;
    for (; it + 7 < end; it += 8) {
        int v[8]; float2 hv[8];
        #pragma unroll
        for (int u = 0; u < 8; ++u) v[u] = sedge[it + u];
        #pragma unroll
        for (int u = 0; u < 8; ++u)
            hv[u] = *(const float2*)(h_in + (v[u] & 0xFFFF) * BH + col);
        #pragma unroll
        for (int u = 0; u < 8; ++u) {
            int ty = v[u] >> 16;
            float wg = (ty == 0) ? e0 : (ty == 1 ? e1 : e2);
            acc.x += wg * hv[u].x; acc.y += wg * hv[u].y;
        }
    }
    for (; it < end; ++it) {
        int v = sedge[it];
        int ty = v >> 16;
        float wg = (ty == 0) ? e0 : (ty == 1 ? e1 : e2);
        float2 hv = *(const float2*)(h_in + (v & 0xFFFF) * BH + col);
        acc.x += wg * hv.x; acc.y += wg * hv.y;
    }
    int b = col >> 4, k0 = col & 15;
    aggS[node][b*17 + k0]     = acc.x * ISD;
    aggS[node][b*17 + k0 + 1] = acc.y * ISD;
    __syncthreads();
    int en = t >> 7, c2 = (t & 127) * 2;
    int eb = c2 >> 4, ek = c2 & 15;
    const float* arow = aggS[en] + eb * 17;
    float o0 = 0.f, o1 = 0.f;
    #pragma unroll
    for (int k = 0; k < 16; ++k) {
        float av = arow[k];
        o0 += av * Wl[k*16 + ek];
        o1 += av * Wl[k*16 + ek + 1];
    }
    int ed = blockIdx.x * 2 + en;
    float2 r;
    r.x = o0 > 0.f ? o0 : 0.f;
    r.y = o1 > 0.f ? o1 : 0.f;
    *(float2*)(h_out + ed*BH + c2) = r;
}

// ---------------- hout[n][b*3+p] = sum_k h2[n][b*16+k] * W_out[k][p] --------
__global__ void hout_kernel(const float* __restrict__ h2, const float* __restrict__ Wout,
                            float* __restrict__ hout) {
    __shared__ float Wo[48];
    int t = threadIdx.x;
    if (t < 48) Wo[t] = Wout[t];
    __syncthreads();
    int id = blockIdx.x * 256 + t;
    int n = id >> 4, b = id & 15;
    const float* hr = h2 + n*BH + b*HDIM;
    float s0=0.f, s1=0.f, s2=0.f;
    #pragma unroll
    for (int k = 0; k < 16; ++k) {
        float v = hr[k];
        s0 += v*Wo[k*3+0]; s1 += v*Wo[k*3+1]; s2 += v*Wo[k*3+2];
    }
    float* o = hout + n*48 + b*3;
    o[0]=s0; o[1]=s1; o[2]=s2;
}

// ---------------- a, c for first N edges ------------------------------------
__global__ void ac_kernel(const float* __restrict__ hout, const int* __restrict__ esrc,
                          const int* __restrict__ edst, const float* __restrict__ invF,
                          float* __restrict__ a, float* __restrict__ c) {
    __shared__ float iF[144];
    int t = threadIdx.x;
    if (t < 144) iF[t] = invF[t];
    __syncthreads();
    int id = blockIdx.x * 256 + t;
    int i = id >> 4, b = id & 15;
    int s = esrc[i], d = edst[i];
    float a0 = hout[s*48+b*3+0] - hout[d*48+b*3+0];
    float a1 = hout[s*48+b*3+1] - hout[d*48+b*3+1];
    float a2 = hout[s*48+b*3+2] - hout[d*48+b*3+2];
    float* ap = a + i*48 + b*3;
    ap[0]=a0; ap[1]=a1; ap[2]=a2;
    const float* m = iF + b*9;
    float* cp = c + i*48 + b*3;
    cp[0] = m[0]*a0 + m[1]*a1 + m[2]*a2;
    cp[1] = m[3]*a0 + m[4]*a1 + m[5]*a2;
    cp[2] = m[6]*a0 + m[7]*a1 + m[8]*a2;
}

// ---------------- fused stress: t-partial GEMM + c-contraction --------------
// stress[b,p,q] = sum_j (sum_i W2[i,j] a[i,bp]) c[j,bq].  Linear in the
// per-block partial t: each block (64-i strip x 128-j tile) contracts its own
// t-tile against c (read direct from global; c = 786 KB, L2-resident) and
// STORES 144 partials to P[idx][block] — no global atomics (v1's 147K
// contended fp atomics onto 144 addrs = the 428 us stall).
// Occupancy: LDS 12 KB + launch_bounds(256,6) -> 24 waves/CU (v0 had 8):
// cross-wave TLP covers W2 load latency over the 8-row rotating prefetch.
// Epilogue wave-reduce via DPP (VALU, 4 SIMDs) instead of 216 ds_swizzle
// per wave contending the single per-CU LDS pipe.
__global__ __launch_bounds__(256, 6)
void stress_fused_kernel(const float* __restrict__ W2, const float* __restrict__ a,
                         const float* __restrict__ c, float* __restrict__ P) {
    __shared__ float sa[64 * 48];        // 12 KB a-strip [row][col]
    int t = threadIdx.x;
    int lane = t & 63;
    int wave = t >> 6;          // 0..3, wave owns cols cg..cg+11 (disjoint b)
    int cg   = wave * 12;
    int jb    = (blockIdx.x & 31) * 128;
    int strip = blockIdx.x >> 5;         // 0..63
    int i0    = strip * 64;
    // stage a-strip: 3072 floats = 768 float4
    {
        const float4* ga = (const float4*)(a + (size_t)i0 * 48);
        float4* la = (float4*)sa;
        #pragma unroll
        for (int k = 0; k < 3; ++k) la[t + k * 256] = ga[t + k * 256];
    }
    __syncthreads();
    int j = jb + lane * 2;
    const float* w2p = W2 + (size_t)i0 * N_NODES + j;
    float4 acc[2][3];
    #pragma unroll
    for (int jj = 0; jj < 2; ++jj)
        #pragma unroll
        for (int q = 0; q < 3; ++q) acc[jj][q] = make_float4(0.f,0.f,0.f,0.f);
    float2 w[8];
    #pragma unroll
    for (int u = 0; u < 8; ++u)
        w[u] = *(const float2*)(w2p + (size_t)u * N_NODES);
    #pragma unroll 1
    for (int base = 0; base < 64; base += 8) {
        // prefetch next 8 rows (clamped tail loads are harmless — never FMA'd)
        float2 wn[8];
        #pragma unroll
        for (int u = 0; u < 8; ++u) {
            int r = base + 8 + u; if (r > 63) r = 63;
            wn[u] = *(const float2*)(w2p + (size_t)r * N_NODES);
        }
        // FMA on current 8 rows, a from LDS broadcast (same addr all lanes: free)
        #pragma unroll
        for (int u = 0; u < 8; ++u) {
            const float* ar = &sa[(base + u) * 48 + cg];
            float4 x = *(const float4*)(ar);
            float4 y = *(const float4*)(ar + 4);
            float4 z = *(const float4*)(ar + 8);
            #pragma unroll
            for (int jj = 0; jj < 2; ++jj) {
                float wv = jj == 0 ? w[u].x : w[u].y;
                acc[jj][0].x += wv*x.x; acc[jj][0].y += wv*x.y;
                acc[jj][0].z += wv*x.z; acc[jj][0].w += wv*x.w;
                acc[jj][1].x += wv*y.x; acc[jj][1].y += wv*y.y;
                acc[jj][1].z += wv*y.z; acc[jj][1].w += wv*y.w;
                acc[jj][2].x += wv*z.x; acc[jj][2].y += wv*z.y;
                acc[jj][2].z += wv*z.z; acc[jj][2].w += wv*z.w;
            }
        }
        #pragma unroll
        for (int u = 0; u < 8; ++u) w[u] = wn[u];
    }
    // epilogue: contract t-tile with c read direct from global (L2-resident).
    // thread's 2 j-values x 12 cols; cvp 16B-aligned (row*192B + cg*4B, cg%12==0
    // -> 48B multiples).
    float s[36];
    #pragma unroll
    for (int m = 0; m < 36; ++m) s[m] = 0.f;
    #pragma unroll
    for (int jj = 0; jj < 2; ++jj) {
        const float* cvp = c + (size_t)(jb + lane * 2 + jj) * 48 + cg;
        float4 c0 = *(const float4*)(cvp);
        float4 c1 = *(const float4*)(cvp + 4);
        float4 c2 = *(const float4*)(cvp + 8);
        float cv[12] = {c0.x,c0.y,c0.z,c0.w, c1.x,c1.y,c1.z,c1.w, c2.x,c2.y,c2.z,c2.w};
        #pragma unroll
        for (int cc = 0; cc < 12; ++cc) {
            float tv = f4get(acc[jj][cc >> 2], cc & 3);
            int qb = (cc / 3) * 3;
            s[cc*3+0] += tv * cv[qb+0];
            s[cc*3+1] += tv * cv[qb+1];
            s[cc*3+2] += tv * cv[qb+2];
        }
    }
    // DPP wave sum (total valid in lane 63); lanes hold disjoint j
    #pragma unroll
    for (int m = 0; m < 36; ++m) s[m] = wave_sum64(s[m]);
    // waves own disjoint b-groups -> 144 plain stores per block, no atomics
    if (lane == 63) {
        #pragma unroll
        for (int m = 0; m < 36; ++m) {
            int cc = m / 3, q = m % 3;
            int bp = cg + cc;
            P[(size_t)((bp / 3) * 9 + (bp % 3) * 3 + q) * NBSTRESS + blockIdx.x] = s[m];
        }
    }
}

// ---------------- sum P[idx][0..2047] -> out[idx] ---------------------------
__global__ void stress_reduce_kernel(const float* __restrict__ P, float* __restrict__ out) {
    __shared__ float wsum[4];
    int t = threadIdx.x, lane = t & 63, wave = t >> 6;
    const float* p = P + (size_t)blockIdx.x * NBSTRESS;
    float4 v0 = *(const float4*)(p + t * 8);
    float4 v1 = *(const float4*)(p + t * 8 + 4);
    float s = v0.x+v0.y+v0.z+v0.w + v1.x+v1.y+v1.z+v1.w;
    #pragma unroll
    for (int o = 1; o < 64; o <<= 1) s += __shfl_xor(s, o);
    if (lane == 0) wsum[wave] = s;
    __syncthreads();
    if (t == 0) out[blockIdx.x] = wsum[0] + wsum[1] + wsum[2] + wsum[3];
}

extern "C" void kernel_launch(void* const* d_in, const int* in_sizes, int n_in,
                              void* d_out, int out_size, void* d_ws, size_t ws_size,
                              hipStream_t stream) {
    const float* F     = (const float*)d_in[0];
    const float* pos   = (const float*)d_in[1];
    const int*   esrc  = (const int*)d_in[2];
    const int*   edst  = (const int*)d_in[3];
    const int*   etyp  = (const int*)d_in[4];
    const float* W_in  = (const float*)d_in[5];
    const float* fc1_0 = (const float*)d_in[6];
    const float* fc2_0 = (const float*)d_in[7];
    const float* W_0   = (const float*)d_in[8];
    const float* fc1_1 = (const float*)d_in[9];
    const float* fc2_1 = (const float*)d_in[10];
    const float* W_1   = (const float*)d_in[11];
    const float* W_out = (const float*)d_in[12];
    const float* w2    = (const float*)d_in[13];
    float* out = (float*)d_out;

    float* ws   = (float*)d_ws;
    float* ew   = ws;                     // 6
    float* G    = ws + 16;                // 768
    float* invF = ws + 800;               // 144
    float* bufA = ws + 1024;              // N*256
    float* bufB = bufA + N_NODES*BH;      // N*256
    float* hout = bufB + N_NODES*BH;      // N*48
    float* aArr = hout + N_NODES*48;      // N*48
    float* cArr = aArr + N_NODES*48;      // N*48
    int* cnt    = (int*)(cArr + N_NODES*48);
    int* off    = cnt + N_NODES;          // N+1
    int* cursor = off + N_NODES + 1;      // N
    int* sedge  = cursor + N_NODES;       // E
    float* P    = (float*)(sedge + N_EDGES);   // 144 * NBSTRESS (1.2 MB)

    setup_kernel<<<1, 256, 0, stream>>>(F, W_in, fc1_0, fc2_0, fc1_1, fc2_1, ew, G, invF, out, cnt);
    h0_hist_kernel<<<1536, 256, 0, stream>>>(pos, G, bufA, edst, cnt);
    scan_kernel<<<1, 256, 0, stream>>>(cnt, off, cursor);
    fill_kernel<<<512, 256, 0, stream>>>(esrc, edst, etyp, cursor, sedge);
    layer_kernel<<<2048, 256, 0, stream>>>(bufA, bufB, off, sedge, ew,     W_0);
    layer_kernel<<<2048, 256, 0, stream>>>(bufB, bufA, off, sedge, ew + 3, W_1);
    hout_kernel<<<256, 256, 0, stream>>>(bufA, W_out, hout);
    ac_kernel<<<256, 256, 0, stream>>>(hout, esrc, edst, invF, aArr, cArr);
    stress_fused_kernel<<<NBSTRESS, 256, 0, stream>>>(w2, aArr, cArr, P);
    stress_reduce_kernel<<<144, 256, 0, stream>>>(P, out);
}